// Round 3
// baseline (98.110 us; speedup 1.0000x reference)
//
#include <hip/hip_runtime.h>
#include <math.h>

#define NUM_RBF 64
#define N_GRAPHS 64

typedef int   int4v   __attribute__((ext_vector_type(4)));
typedef float float4v __attribute__((ext_vector_type(4)));

// Model (r0-r2 evidence): edge kernel is bound by L2 random 16B request
// THROUGHPUT (~178 req/us chip-wide), not latency -- warming (r2) and
// MLP/occupancy changes were all null; VALUBusy 7.5%, HBM 2.6%.
// Request budget: 3.2M rec gathers + ~1.4M Ctab gathers + 0.2M idx lines.
// This version deletes the Ctab share (-30%): the 160,000B fused table is
// staged once per CU into dynamic LDS (1024-thread blocks, 1 block/CU,
// 256 blocks) and window reads become ds_read_b128. Staging overlaps the
// first quad's gathers. Warm loop dropped (neutral). Partials+reduce kept
// (r1 showed same-address global atomics cost +21us).

__global__ __launch_bounds__(256) void prologue_kernel(
    const float4v* __restrict__ p, const float4v* __restrict__ f,
    float4v* __restrict__ C, int n4,
    const float* __restrict__ pos, const int* __restrict__ types,
    const int* __restrict__ batch, float4v* __restrict__ rec, int N)
{
    int i = blockIdx.x * blockDim.x + threadIdx.x;
    if (i < n4) C[i] = p[i] * f[i];
    if (i < N) {
        int bits = (types[i] & 0xFF) | ((batch[i] & 0xFF) << 8);
        float4v r = { pos[3 * i], pos[3 * i + 1], pos[3 * i + 2],
                      __int_as_float(bits) };
        rec[i] = r;
    }
}

#define CUTOFF_F      5.0f
#define GAMMA_F       163.84f                    /* (64/5)^2                  */
#define SPACING_F     (float)(5.0 / 63.0)
#define INV_SPACING_F (float)(63.0 / 5.0)
#define PI_OVER_C_F   (float)(3.14159265358979323846 / 5.0)
#define TWO_GAMMA_S_F (float)(2.0 * 163.84 * 5.0 / 63.0)   /* 26.00635 */
// v = exp(-gamma*s^2) = exp(-(64/63)^2)
#define LN_V          (-(64.0 / 63.0) * (64.0 / 63.0))
#define V_1           (float)exp(LN_V)           /* v    (first ratio factor) */
#define V_2           (float)exp(2.0 * LN_V)     /* v^2  (per-step multiplier)*/

__device__ __forceinline__ void edge_body(
    float4v rs, float4v rd, const float4v* __restrict__ tab, int T,
    float* __restrict__ bins)
{
    const float dx = rd.x - rs.x;
    const float dy = rd.y - rs.y;
    const float dz = rd.z - rs.z;
    const float d  = sqrtf(dx * dx + dy * dy + dz * dz + 1e-12f);
    if (d >= CUTOFF_F) return;

    const int sb = __float_as_int(rs.w);
    const int db = __float_as_int(rd.w);
    const int ts = sb & 0xFF;
    const int td = db & 0xFF;
    const int lo = min(ts, td);
    const int hi = max(ts, td);
    const int base = (lo * T + hi) * NUM_RBF;

    // 12-tap window, start aligned to x4; covers >= +-3.5 spacings
    const float c = d * INV_SPACING_F;
    int a0 = ((int)floorf(c - 3.5f)) & ~3;
    a0 = max(0, min(NUM_RBF - 12, a0));

    const float4v* w = tab + ((base + a0) >> 2);
    const float4v w0 = w[0], w1 = w[1], w2 = w[2];

    // Taps t_k = exp(-gamma*(delta-k*s)^2), k=0..11, anchored at k=5:
    //   up  : t_{k+1} = t_k * m,  m0 = u  * v,  m *= v^2 per step
    //   down: t_{k-1} = t_k * m,  m0 = ui * v,  m *= v^2 per step
    //   u = exp(+2*gamma*s*d5), ui = 1/u, d5 = delta - 5s, v = exp(-gamma*s^2)
    const float delta = d - (float)a0 * SPACING_F;
    const float d5 = delta - 5.0f * SPACING_F;
    const float t5 = __expf(-GAMMA_F * d5 * d5);
    const float x  = TWO_GAMMA_S_F * d5;
    const float u  = __expf(x);
    const float ui = __expf(-x);

    float acc = w1.y * t5;                 // k=5
    float t = t5, m = u * V_1;             // upward k=6..11
    t *= m;  acc += w1.z * t;  m *= V_2;
    t *= m;  acc += w1.w * t;  m *= V_2;
    t *= m;  acc += w2.x * t;  m *= V_2;
    t *= m;  acc += w2.y * t;  m *= V_2;
    t *= m;  acc += w2.z * t;  m *= V_2;
    t *= m;  acc += w2.w * t;
    t = t5;  m = ui * V_1;                 // downward k=4..0
    t *= m;  acc += w1.x * t;  m *= V_2;
    t *= m;  acc += w0.w * t;  m *= V_2;
    t *= m;  acc += w0.z * t;  m *= V_2;
    t *= m;  acc += w0.y * t;  m *= V_2;
    t *= m;  acc += w0.x * t;

    const float fc = 0.5f * (__cosf(PI_OVER_C_F * d) + 1.0f);
    atomicAdd(&bins[(sb >> 8) & 0xFF], acc * fc);
}

template<bool TAB_LDS>
__global__ __launch_bounds__(1024) void edge_energy_kernel(
    const int*     __restrict__ edge_index,
    const float4v* __restrict__ rec,
    const float4v* __restrict__ C4,
    float*         __restrict__ partial,
    int E, int T, int tbl4)
{
    __shared__ float bins[N_GRAPHS];
    extern __shared__ float4v tab4[];          // 160,000 B fused table

    const int nq     = E >> 2;
    const int stride = gridDim.x * blockDim.x;
    const int gid    = blockIdx.x * blockDim.x + threadIdx.x;

    for (int i = threadIdx.x; i < N_GRAPHS; i += blockDim.x) bins[i] = 0.0f;

    // First quad's index loads + 8 record gathers are issued BEFORE the
    // 160KB staging loop so the LDS fill overlaps the gather warm-up.
    const int  q0   = gid;
    const bool has0 = q0 < nq;
    int4v sv = {0,0,0,0}, tv = {0,0,0,0};
    float4v rs0{}, rd0{}, rs1{}, rd1{}, rs2{}, rd2{}, rs3{}, rd3{};
    if (has0) {
        const int e0 = q0 << 2;
        sv = __builtin_nontemporal_load((const int4v*)(edge_index + e0));
        tv = __builtin_nontemporal_load((const int4v*)(edge_index + E + e0));
        rs0 = rec[sv.x]; rd0 = rec[tv.x];
        rs1 = rec[sv.y]; rd1 = rec[tv.y];
        rs2 = rec[sv.z]; rd2 = rec[tv.z];
        rs3 = rec[sv.w]; rd3 = rec[tv.w];
    }
    if constexpr (TAB_LDS) {
        for (int i = threadIdx.x; i < tbl4; i += blockDim.x)
            tab4[i] = C4[i];
    }
    __syncthreads();

    const float4v* tp;
    if constexpr (TAB_LDS) tp = tab4; else tp = C4;

    if (has0) {
        edge_body(rs0, rd0, tp, T, bins);
        edge_body(rs1, rd1, tp, T, bins);
        edge_body(rs2, rd2, tp, T, bins);
        edge_body(rs3, rd3, tp, T, bins);
    }

    for (int q = q0 + stride; q < nq; q += stride) {
        const int e0 = q << 2;
        const int4v s2 = __builtin_nontemporal_load(
            (const int4v*)(edge_index + e0));
        const int4v t2 = __builtin_nontemporal_load(
            (const int4v*)(edge_index + E + e0));
        const float4v a0 = rec[s2.x], b0 = rec[t2.x];
        const float4v a1 = rec[s2.y], b1 = rec[t2.y];
        const float4v a2 = rec[s2.z], b2 = rec[t2.z];
        const float4v a3 = rec[s2.w], b3 = rec[t2.w];
        edge_body(a0, b0, tp, T, bins);
        edge_body(a1, b1, tp, T, bins);
        edge_body(a2, b2, tp, T, bins);
        edge_body(a3, b3, tp, T, bins);
    }

    if (gid == 0) {                       // tail edges (E % 4)
        for (int e = nq << 2; e < E; ++e) {
            const float4v rs = rec[edge_index[e]];
            const float4v rd = rec[edge_index[E + e]];
            edge_body(rs, rd, tp, T, bins);
        }
    }

    __syncthreads();
    for (int i = threadIdx.x; i < N_GRAPHS; i += blockDim.x)
        partial[blockIdx.x * N_GRAPHS + i] = bins[i];
}

__global__ __launch_bounds__(256) void reduce_kernel(
    const float* __restrict__ partial, float* __restrict__ out, int nblocks)
{
    const int g = blockIdx.x;
    float s = 0.0f;
    for (int i = threadIdx.x; i < nblocks; i += blockDim.x)
        s += partial[i * N_GRAPHS + g];

    for (int off = 32; off > 0; off >>= 1)
        s += __shfl_down(s, off, 64);

    __shared__ float red[4];
    const int wave = threadIdx.x >> 6;
    const int lane = threadIdx.x & 63;
    if (lane == 0) red[wave] = s;
    __syncthreads();
    if (threadIdx.x == 0)
        out[g] = red[0] + red[1] + red[2] + red[3];
}

extern "C" void kernel_launch(void* const* d_in, const int* in_sizes, int n_in,
                              void* d_out, int out_size, void* d_ws, size_t ws_size,
                              hipStream_t stream) {
    const float* pos            = (const float*)d_in[0];
    const float* rbf_params     = (const float*)d_in[1];
    const float* radial_filters = (const float*)d_in[2];
    const int*   edge_index     = (const int*)d_in[3];
    const int*   atom_types     = (const int*)d_in[4];
    const int*   batch          = (const int*)d_in[5];
    float*       out            = (float*)d_out;

    const int E = in_sizes[3] / 2;
    const int N = in_sizes[4];
    int T = 1;
    while ((T + 1) * (T + 1) * NUM_RBF <= in_sizes[1]) ++T;
    const int tbl_elems = T * T * NUM_RBF;          // multiple of 4
    const int tbl4      = tbl_elems / 4;
    const size_t tbl_bytes = (size_t)tbl_elems * sizeof(float);

    // workspace layout (256B aligned): [table | node recs | partials]
    float*   Ctab    = (float*)d_ws;
    float4v* recs    = (float4v*)((char*)d_ws + (tbl_bytes + 255) / 256 * 256);
    float*   partial = (float*)((char*)recs + (size_t)N * 16);

    // opt-in to >64KB dynamic LDS once; fall back to global-table variant
    // if the attribute is rejected (e.g. table too large for LDS)
    static int lds_ok = -1;
    if (lds_ok < 0) {
        auto fn = edge_energy_kernel<true>;
        lds_ok = (tbl_bytes <= 160 * 1024 - 1024 &&
                  hipFuncSetAttribute((const void*)fn,
                      hipFuncAttributeMaxDynamicSharedMemorySize,
                      (int)tbl_bytes) == hipSuccess) ? 1 : 0;
    }

    const int nq = E >> 2;
    int nblocks = (nq + 1023) / 1024;               // 1024-thread blocks
    if (nblocks > 256) nblocks = 256;               // 1 block/CU (160KB LDS)
    const size_t part_off = (size_t)((char*)partial - (char*)d_ws);
    const size_t avail = (ws_size > part_off) ? (ws_size - part_off) : 0;
    const int maxb = (int)(avail / (N_GRAPHS * sizeof(float)));
    if (nblocks > maxb) nblocks = maxb > 0 ? maxb : 1;
    if (nblocks < 1) nblocks = 1;

    const int pro_n = max(tbl_elems / 4, N);
    prologue_kernel<<<(pro_n + 255) / 256, 256, 0, stream>>>(
        (const float4v*)rbf_params, (const float4v*)radial_filters,
        (float4v*)Ctab, tbl_elems / 4, pos, atom_types, batch, recs, N);

    if (lds_ok)
        edge_energy_kernel<true><<<nblocks, 1024, tbl_bytes, stream>>>(
            edge_index, recs, (const float4v*)Ctab, partial, E, T, tbl4);
    else
        edge_energy_kernel<false><<<nblocks, 1024, 0, stream>>>(
            edge_index, recs, (const float4v*)Ctab, partial, E, T, tbl4);

    reduce_kernel<<<N_GRAPHS, 256, 0, stream>>>(partial, out, nblocks);
}